// Round 4
// baseline (195.474 us; speedup 1.0000x reference)
//
#include <hip/hip_runtime.h>
#include <math.h>

#define NCELL 16
#define BLOCK 256
#define H16 0.0625f
#define SENT 1e30f

// ---------------------------------------------------------------------------
// Host-side reproduction of B_NP = Vh[rank:].T from numpy.linalg.svd(L).
// For (m,n)=(15,32) with n >= mnthr(=int(15*11/6)=27), LAPACK dgesdd takes
// Path 9t (LQ first): rows 15..31 of Vh are exactly rows 15..31 of the full
// orthogonal factor Q from the Householder LQ factorization of L
// (dgelqf + dorglq), untouched by the bidiagonal-SVD stage (dormbr only
// updates the first M rows). Reproduce dgelq2/dlarfg in double precision;
// dorgl2 applies H(15) first ... H(1) last to unit rows e_{15+q}.
// ---------------------------------------------------------------------------
struct BMat { float v[32][17]; };
static BMat g_B;

static struct BInitializer {
  BInitializer() {
    double A[15][32];
    for (int r = 0; r < 15; ++r)
      for (int j = 0; j < 32; ++j) A[r][j] = 0.0;
    for (int k = 1; k <= 15; ++k) {
      double xk = (double)k / 16.0;
      A[k - 1][2 * (k - 1)]     =  xk;
      A[k - 1][2 * (k - 1) + 1] =  1.0;
      A[k - 1][2 * k]           = -xk;
      A[k - 1][2 * k + 1]       = -1.0;
    }
    double V[15][32], tau[15];
    for (int i = 0; i < 15; ++i) {
      double alpha = A[i][i];
      double xn2 = 0.0;
      for (int j = i + 1; j < 32; ++j) xn2 += A[i][j] * A[i][j];
      for (int j = 0; j < 32; ++j) V[i][j] = 0.0;
      V[i][i] = 1.0;
      if (xn2 == 0.0) { tau[i] = 0.0; continue; }
      double beta = -copysign(sqrt(alpha * alpha + xn2), alpha);
      tau[i] = (beta - alpha) / beta;
      double s = 1.0 / (alpha - beta);
      for (int j = i + 1; j < 32; ++j) V[i][j] = A[i][j] * s;
      A[i][i] = beta;
      for (int r = i + 1; r < 15; ++r) {
        double dot = 0.0;
        for (int j = i; j < 32; ++j) dot += A[r][j] * V[i][j];
        double t = tau[i] * dot;
        for (int j = i; j < 32; ++j) A[r][j] -= t * V[i][j];
      }
    }
    // row (15+q) of Q = e^T H(15)...H(1): apply H(15) first, ..., H(1) last.
    for (int q = 0; q < 17; ++q) {
      double u[32];
      for (int p = 0; p < 32; ++p) u[p] = 0.0;
      u[15 + q] = 1.0;
      for (int i = 14; i >= 0; --i) {
        double dot = 0.0;
        for (int p = i; p < 32; ++p) dot += u[p] * V[i][p];
        double t = tau[i] * dot;
        for (int p = i; p < 32; ++p) u[p] -= t * V[i][p];
      }
      for (int p = 0; p < 32; ++p) g_B.v[p][q] = (float)u[p];
    }
  }
} g_binit;

// ---------------------------------------------------------------------------
// Closed-form CPAB flow. Velocity field is continuous => sign(v) constant
// along a trajectory => monotone motion, each cell crossed at most once,
// phase = log(v_exit / v_entry) telescopes. Per block, build per-direction
// tables (forward field + mirrored field for left-moving flow):
//   vb[k]  : velocity at boundary k/16
//   lvb[k] : log(vb[k])            (NaN/-inf when vb<=0; always guarded)
//   pr[k]  : prefix sum of clamped cell traversal times min(tau_c, 2)
// Per point: 1 log + branchless 15-step search over register tables + 1 exp.
// ---------------------------------------------------------------------------
__global__ __launch_bounds__(BLOCK) void
cpab_kernel(const float4* __restrict__ x4, const float* __restrict__ theta,
            float4* __restrict__ zout, float4* __restrict__ pout, BMat B) {
  __shared__ float Ash[32];
  __shared__ float4 cellT[2][16];   // {a, b, 1/a_safe, b/a_safe}
  __shared__ float vbT[2][17];
  __shared__ float lvbT[2][17];
  __shared__ float prT[2][17];

  const int tid = threadIdx.x;

  if (tid < 32) {
    float acc = 0.0f;
#pragma unroll
    for (int q = 0; q < 17; ++q) acc += theta[q] * B.v[tid][q];
    Ash[tid] = acc;
  }
  __syncthreads();

  // cells: d=0 forward; d=1 mirrored (y=1-x): a' = a_{15-c}, b' = -(a+b)_{15-c}
  if (tid < 32) {
    int d = tid >> 4, c = tid & 15;
    int cs = d ? 15 - c : c;
    float a = Ash[2 * cs];
    float b = d ? -(Ash[2 * cs] + Ash[2 * cs + 1]) : Ash[2 * cs + 1];
    float as = (fabsf(a) < 1e-12f) ? 1.0f : a;
    float ia = 1.0f / as;
    cellT[d][c] = make_float4(a, b, ia, b * ia);
  }
  // boundary velocities (uses Ash directly; right-adjacent cell, continuity)
  if (tid >= 32 && tid < 66) {
    int t2 = tid - 32;
    int d = (t2 >= 17) ? 1 : 0, k = d ? t2 - 17 : t2;
    int c = min(k, 15);
    int cs = d ? 15 - c : c;
    float a = Ash[2 * cs];
    float b = d ? -(Ash[2 * cs] + Ash[2 * cs + 1]) : Ash[2 * cs + 1];
    float v = fmaf(a, (float)k * H16, b);
    vbT[d][k] = v;
    lvbT[d][k] = __logf(v);
  }
  __syncthreads();

  // per-cell traversal times (clamped to [0,2]; 2 == "blocked/over-budget")
  if (tid < 32) {
    int d = tid >> 4, c = tid & 15;
    float a = cellT[d][c].x, ia = cellT[d][c].z;
    float va = vbT[d][c], vb = vbT[d][c + 1];
    float tau;
    if (va > 0.0f && vb > 0.0f)
      tau = (fabsf(a) < 1e-12f) ? H16 / va : (lvbT[d][c + 1] - lvbT[d][c]) * ia;
    else
      tau = 2.0f;
    tau = fminf(fmaxf(tau, 0.0f), 2.0f);
    prT[d][c + 1] = tau;  // temp; prefixed below
  }
  __syncthreads();
  if (tid < 2) {
    float s = 0.0f;
    prT[tid][0] = 0.0f;
    for (int c = 0; c < 16; ++c) { s += prT[tid][c + 1]; prT[tid][c + 1] = s; }
  }
  __syncthreads();

  // hoist prefix tables into registers (uniform broadcast reads, static idx)
  float prF[16], prM[16];
#pragma unroll
  for (int k = 0; k < 16; ++k) { prF[k] = prT[0][k]; prM[k] = prT[1][k]; }

  const int gid = blockIdx.x * BLOCK + tid;
  const float4 xs = x4[gid];
  float xin[4] = {xs.x, xs.y, xs.z, xs.w};
  float zr[4], ph[4];

#pragma unroll
  for (int p = 0; p < 4; ++p) {
    float x = fminf(fmaxf(xin[p], 1e-7f), 1.0f - 1e-7f);
    int c0 = min((int)(x * 16.0f), 15);
    float4 cf = cellT[0][c0];
    float vraw = fmaf(cf.x, x, cf.y);
    bool mir = vraw < 0.0f;          // left-moving -> work in mirrored coords
    int cw = mir ? 15 - c0 : c0;
    float xw = mir ? 1.0f - x : x;
    float a2 = cf.x;                  // mirrored a == forward a (same cell)
    float ia2 = cf.z;
    float v0 = mir ? -vraw : vraw;    // >= 0 in working coords
    bool az = fabsf(a2) < 1e-12f;
    float lv0 = __logf(v0);

    const float* vb  = vbT[mir ? 1 : 0];
    const float* lvb = lvbT[mir ? 1 : 0];
    const float* pr  = prT[mir ? 1 : 0];

    // time to reach first boundary (cw+1) in working coords
    float xb = (float)(cw + 1) * H16;
    float vbn = vb[cw + 1];
    float rv = __builtin_amdgcn_rcpf(fmaxf(v0, 1e-30f));
    float t0 = az ? (xb - xw) * rv : (lvb[cw + 1] - lv0) * ia2;
    if (v0 < 1e-15f || vbn <= 0.0f) t0 = SENT;  // stationary / blocked

    // branchless search: m = last cell entered with cumulative time <= 1
    float prc = pr[cw + 1];
    float Tstar = 1.0f - t0 + prc;   // pr[k] <= Tstar <=> t_enter(k) <= 1
    int m = cw;
#pragma unroll
    for (int k = 1; k <= 15; ++k) {
      float prk = mir ? prM[k] : prF[k];
      if ((k > cw) && (prk <= Tstar)) ++m;
    }
    bool moved = (m != cw);
    float4 cmv = cellT[mir ? 1 : 0][m];
    float t_enter = moved ? t0 + (pr[m] - prc) : 0.0f;
    float t_rem = 1.0f - t_enter;
    float xe = moved ? (float)m * H16 : xw;
    float ve = moved ? vb[m] : v0;
    bool az3 = fabsf(cmv.x) < 1e-12f;
    float zw = az3 ? fmaf(ve, t_rem, xe)
                   : fmaf(xe + cmv.w, __expf(cmv.x * t_rem), -cmv.w);
    zr[p] = mir ? 1.0f - zw : zw;
    // phase = log(v_entry(m)/v0) + a_m * t_rem  (telescoped integral of a)
    ph[p] = (moved ? lvb[m] - lv0 : 0.0f) + cmv.x * t_rem;
  }

  zout[gid] = make_float4(zr[0], zr[1], zr[2], zr[3]);
  pout[gid] = make_float4(ph[0], ph[1], ph[2], ph[3]);
}

extern "C" void kernel_launch(void* const* d_in, const int* in_sizes, int n_in,
                              void* d_out, int out_size, void* d_ws, size_t ws_size,
                              hipStream_t stream) {
  const float4* x4 = (const float4*)d_in[0];
  const float* theta = (const float*)d_in[1];
  float* out = (float*)d_out;
  const int npts = in_sizes[0];  // 16777216
  const int groups = npts / 4;
  const int grid = groups / BLOCK;
  cpab_kernel<<<grid, BLOCK, 0, stream>>>(
      x4, theta, (float4*)out, (float4*)(out + npts), g_B);
}

// Round 5
// 185.147 us; speedup vs baseline: 1.0558x; 1.0558x over previous
//
#include <hip/hip_runtime.h>
#include <math.h>

#define BLOCK 256
#define H16 0.0625f
#define SENT 1e30f

// ---------------------------------------------------------------------------
// Host-side reproduction of B_NP = Vh[rank:].T from numpy.linalg.svd(L).
// For (m,n)=(15,32) with n >= mnthr(=int(15*11/6)=27), LAPACK dgesdd takes
// Path 9t (LQ first): rows 15..31 of Vh are exactly rows 15..31 of the full
// orthogonal factor Q from the Householder LQ factorization of L
// (dgelqf + dorglq), untouched by the bidiagonal-SVD stage (dormbr only
// updates the first M rows). Reproduce dgelq2/dlarfg in double precision;
// dorgl2 applies H(15) first ... H(1) last to unit rows e_{15+q}.
// ---------------------------------------------------------------------------
struct BMat { float v[32][17]; };
static BMat g_B;

static struct BInitializer {
  BInitializer() {
    double A[15][32];
    for (int r = 0; r < 15; ++r)
      for (int j = 0; j < 32; ++j) A[r][j] = 0.0;
    for (int k = 1; k <= 15; ++k) {
      double xk = (double)k / 16.0;
      A[k - 1][2 * (k - 1)]     =  xk;
      A[k - 1][2 * (k - 1) + 1] =  1.0;
      A[k - 1][2 * k]           = -xk;
      A[k - 1][2 * k + 1]       = -1.0;
    }
    double V[15][32], tau[15];
    for (int i = 0; i < 15; ++i) {
      double alpha = A[i][i];
      double xn2 = 0.0;
      for (int j = i + 1; j < 32; ++j) xn2 += A[i][j] * A[i][j];
      for (int j = 0; j < 32; ++j) V[i][j] = 0.0;
      V[i][i] = 1.0;
      if (xn2 == 0.0) { tau[i] = 0.0; continue; }
      double beta = -copysign(sqrt(alpha * alpha + xn2), alpha);
      tau[i] = (beta - alpha) / beta;
      double s = 1.0 / (alpha - beta);
      for (int j = i + 1; j < 32; ++j) V[i][j] = A[i][j] * s;
      A[i][i] = beta;
      for (int r = i + 1; r < 15; ++r) {
        double dot = 0.0;
        for (int j = i; j < 32; ++j) dot += A[r][j] * V[i][j];
        double t = tau[i] * dot;
        for (int j = i; j < 32; ++j) A[r][j] -= t * V[i][j];
      }
    }
    for (int q = 0; q < 17; ++q) {
      double u[32];
      for (int p = 0; p < 32; ++p) u[p] = 0.0;
      u[15 + q] = 1.0;
      for (int i = 14; i >= 0; --i) {
        double dot = 0.0;
        for (int p = i; p < 32; ++p) dot += u[p] * V[i][p];
        double t = tau[i] * dot;
        for (int p = i; p < 32; ++p) u[p] -= t * V[i][p];
      }
      for (int p = 0; p < 32; ++p) g_B.v[p][q] = (float)u[p];
    }
  }
} g_binit;

// ---------------------------------------------------------------------------
// Closed-form CPAB flow, LDS-lean variant. Single packed per-boundary table
//   G[d][k] = { vb_k, log(vb_k), pr_k (prefix of clamped cell times), a_cell }
// for d=0 forward, d=1 mirrored (y=1-x: a'=a_{15-c}, b'=-(a+b)_{15-c}).
// Per point: 2x ds_read_b128 + 4-probe binary search (b32) + 1x b128,
// 1 log + 1 exp + rcp's. Uniform control flow.
// ---------------------------------------------------------------------------
__global__ __launch_bounds__(BLOCK) void
cpab_kernel(const float4* __restrict__ x4, const float* __restrict__ theta,
            float4* __restrict__ zout, float4* __restrict__ pout, BMat B) {
  __shared__ float Ash[32];
  __shared__ float4 G[2][17];

  const int tid = threadIdx.x;

  if (tid < 32) {
    float acc = 0.0f;
#pragma unroll
    for (int q = 0; q < 17; ++q) acc += theta[q] * B.v[tid][q];
    Ash[tid] = acc;
  }
  __syncthreads();

  // boundary k of direction d: velocity, log, and owning-cell slope
  if (tid < 34) {
    int d = (tid >= 17) ? 1 : 0, k = d ? tid - 17 : tid;
    int c = min(k, 15), cs = d ? 15 - c : c;
    float a = Ash[2 * cs];
    float b = d ? -(Ash[2 * cs] + Ash[2 * cs + 1]) : Ash[2 * cs + 1];
    float v = fmaf(a, (float)k * H16, b);
    G[d][k].x = v;
    G[d][k].y = __logf(v);
    G[d][k].w = a;
  }
  __syncthreads();

  // per-cell traversal time (clamped to [0,2]; 2 == blocked/over-budget)
  if (tid < 32) {
    int d = tid >> 4, c = tid & 15;
    float a = G[d][c].w;
    float va = G[d][c].x, vb = G[d][c + 1].x;
    float tau;
    if (va > 0.0f && vb > 0.0f) {
      bool az = fabsf(a) < 1e-12f;
      tau = az ? H16 / va : (G[d][c + 1].y - G[d][c].y) / a;
    } else {
      tau = 2.0f;
    }
    tau = fminf(fmaxf(tau, 0.0f), 2.0f);
    G[d][c + 1].z = tau;   // temp; prefixed below (distinct word vs .x/.y reads)
  }
  __syncthreads();
  if (tid < 2) {
    float s = 0.0f;
    G[tid][0].z = 0.0f;
    for (int c = 1; c <= 16; ++c) { s += G[tid][c].z; G[tid][c].z = s; }
  }
  __syncthreads();

  const int gid = blockIdx.x * BLOCK + tid;
  const float4 xs = x4[gid];
  float xin[4] = {xs.x, xs.y, xs.z, xs.w};
  float zr[4], ph[4];

#pragma unroll
  for (int p = 0; p < 4; ++p) {
    float x = fminf(fmaxf(xin[p], 1e-7f), 1.0f - 1e-7f);
    int c0 = min((int)(x * 16.0f), 15);
    float4 g0 = G[0][c0];                       // b128: vb,lvb,pr,a (forward)
    float a = g0.w;
    float vraw = fmaf(a, x - (float)c0 * H16, g0.x);  // x-c0*h exact (Sterbenz)
    bool mir = vraw < 0.0f;                     // left-moving -> mirrored coords
    int cw = mir ? 15 - c0 : c0;
    float xw = mir ? 1.0f - x : x;
    float v0 = mir ? -vraw : vraw;              // >= 0 in working coords
    float lv0 = __logf(v0);
    bool az = fabsf(a) < 1e-12f;
    float ia = __builtin_amdgcn_rcpf(az ? 1.0f : a);
    const float4* Gd = G[mir ? 1 : 0];

    float4 gb = Gd[cw + 1];                     // b128: vbn, lvbn, prc, -
    float xb = (float)(cw + 1) * H16;
    float rv = __builtin_amdgcn_rcpf(fmaxf(v0, 1e-30f));
    float t0 = az ? (xb - xw) * rv : (gb.y - lv0) * ia;
    if (v0 < 1e-15f || gb.x <= 0.0f) t0 = SENT; // stationary / blocked ahead

    // m = last boundary k in [0,15] with pr[k] <= Tstar  (pr sorted ascending)
    float Tstar = 1.0f - t0 + gb.z;
    int m = 0;
    float prm = 0.0f;                           // pr[0] == 0
#pragma unroll
    for (int s = 8; s >= 1; s >>= 1) {
      int cand = m + s;
      float pv = Gd[cand].z;                    // dynamic b32 probe
      if (pv <= Tstar) { m = cand; prm = pv; }
    }
    bool moved = m > cw;
    int mf = moved ? m : cw;
    float4 gm = Gd[mf];                         // b128: vbE, lvbE, prE, a_m
    float am = gm.w;
    bool az3 = fabsf(am) < 1e-12f;
    float iam = __builtin_amdgcn_rcpf(az3 ? 1.0f : am);
    float boa = fmaf(gm.x, iam, -(float)mf * H16);  // b/a from left boundary
    float t_rem = moved ? (Tstar - prm) : 1.0f; // == 1 - t_enter (algebraic)
    float xe = moved ? (float)mf * H16 : xw;
    float ve = moved ? gm.x : v0;
    float zw = az3 ? fmaf(ve, t_rem, xe)
                   : fmaf(xe + boa, __expf(am * t_rem), -boa);
    zr[p] = mir ? 1.0f - zw : zw;
    // phase = log(v_entry(m)/v0) + a_m * t_rem  (telescoped integral of a)
    ph[p] = (moved ? gm.y - lv0 : 0.0f) + am * t_rem;
  }

  zout[gid] = make_float4(zr[0], zr[1], zr[2], zr[3]);
  pout[gid] = make_float4(ph[0], ph[1], ph[2], ph[3]);
}

extern "C" void kernel_launch(void* const* d_in, const int* in_sizes, int n_in,
                              void* d_out, int out_size, void* d_ws, size_t ws_size,
                              hipStream_t stream) {
  const float4* x4 = (const float4*)d_in[0];
  const float* theta = (const float*)d_in[1];
  float* out = (float*)d_out;
  const int npts = in_sizes[0];  // 16777216
  const int groups = npts / 4;
  const int grid = groups / BLOCK;
  cpab_kernel<<<grid, BLOCK, 0, stream>>>(
      x4, theta, (float4*)out, (float4*)(out + npts), g_B);
}

// Round 6
// 184.245 us; speedup vs baseline: 1.0609x; 1.0049x over previous
//
#include <hip/hip_runtime.h>
#include <math.h>

#define BLOCK 256
#define H16 0.0625f
#define SENT 1e30f

// ---------------------------------------------------------------------------
// Host-side reproduction of B_NP = Vh[rank:].T from numpy.linalg.svd(L).
// For (m,n)=(15,32) with n >= mnthr(=int(15*11/6)=27), LAPACK dgesdd takes
// Path 9t (LQ first): rows 15..31 of Vh are exactly rows 15..31 of the full
// orthogonal factor Q from the Householder LQ factorization of L
// (dgelqf + dorglq), untouched by the bidiagonal-SVD stage. Reproduce
// dgelq2/dlarfg in double precision; dorgl2 applies H(15) first..H(1) last.
// ---------------------------------------------------------------------------
struct BMat { float v[32][17]; };
static BMat g_B;

static struct BInitializer {
  BInitializer() {
    double A[15][32];
    for (int r = 0; r < 15; ++r)
      for (int j = 0; j < 32; ++j) A[r][j] = 0.0;
    for (int k = 1; k <= 15; ++k) {
      double xk = (double)k / 16.0;
      A[k - 1][2 * (k - 1)]     =  xk;
      A[k - 1][2 * (k - 1) + 1] =  1.0;
      A[k - 1][2 * k]           = -xk;
      A[k - 1][2 * k + 1]       = -1.0;
    }
    double V[15][32], tau[15];
    for (int i = 0; i < 15; ++i) {
      double alpha = A[i][i];
      double xn2 = 0.0;
      for (int j = i + 1; j < 32; ++j) xn2 += A[i][j] * A[i][j];
      for (int j = 0; j < 32; ++j) V[i][j] = 0.0;
      V[i][i] = 1.0;
      if (xn2 == 0.0) { tau[i] = 0.0; continue; }
      double beta = -copysign(sqrt(alpha * alpha + xn2), alpha);
      tau[i] = (beta - alpha) / beta;
      double s = 1.0 / (alpha - beta);
      for (int j = i + 1; j < 32; ++j) V[i][j] = A[i][j] * s;
      A[i][i] = beta;
      for (int r = i + 1; r < 15; ++r) {
        double dot = 0.0;
        for (int j = i; j < 32; ++j) dot += A[r][j] * V[i][j];
        double t = tau[i] * dot;
        for (int j = i; j < 32; ++j) A[r][j] -= t * V[i][j];
      }
    }
    for (int q = 0; q < 17; ++q) {
      double u[32];
      for (int p = 0; p < 32; ++p) u[p] = 0.0;
      u[15 + q] = 1.0;
      for (int i = 14; i >= 0; --i) {
        double dot = 0.0;
        for (int p = i; p < 32; ++p) dot += u[p] * V[i][p];
        double t = tau[i] * dot;
        for (int p = i; p < 32; ++p) u[p] -= t * V[i][p];
      }
      for (int p = 0; p < 32; ++p) g_B.v[p][q] = (float)u[p];
    }
  }
} g_binit;

// ---------------------------------------------------------------------------
// Closed-form CPAB flow, latency-optimized. Packed per-boundary table
//   G[d][k] = { vb_k, log(vb_k), pr_k (prefix of clamped cell times), a_cell }
// d=0 forward, d=1 mirrored (y=1-x: a'=a_{15-c}, b'=-(a+b)_{15-c}).
// Per point: stage-batched LDS rounds:
//   A: g0 = G[0][c0]                                  (b128)
//   B: gb = Gd[cw+1]  +  pr[4],pr[8],pr[12]           (b128 + 3x b32, concurrent)
//   C: pr[q+1..q+3]                                   (3x b32, static offsets)
//   D: gm = Gd[m]                                     (b128)
// Search range is [0,15]: boundary 16 is not a law switch (cell 15's affine
// law continues), so m=15 integrates identically to "m=16".
// ---------------------------------------------------------------------------
__global__ __launch_bounds__(BLOCK) void
cpab_kernel(const float4* __restrict__ x4, const float* __restrict__ theta,
            float4* __restrict__ zout, float4* __restrict__ pout, BMat B) {
  __shared__ float Ash[32];
  __shared__ float4 G[2][17];

  const int tid = threadIdx.x;

  if (tid < 32) {
    float acc = 0.0f;
#pragma unroll
    for (int q = 0; q < 17; ++q) acc += theta[q] * B.v[tid][q];
    Ash[tid] = acc;
  }
  __syncthreads();

  if (tid < 34) {
    int d = (tid >= 17) ? 1 : 0, k = d ? tid - 17 : tid;
    int c = min(k, 15), cs = d ? 15 - c : c;
    float a = Ash[2 * cs];
    float b = d ? -(Ash[2 * cs] + Ash[2 * cs + 1]) : Ash[2 * cs + 1];
    float v = fmaf(a, (float)k * H16, b);
    G[d][k].x = v;
    G[d][k].y = __logf(v);
    G[d][k].w = a;
  }
  __syncthreads();

  if (tid < 32) {
    int d = tid >> 4, c = tid & 15;
    float a = G[d][c].w;
    float va = G[d][c].x, vb = G[d][c + 1].x;
    float tau;
    if (va > 0.0f && vb > 0.0f) {
      bool az = fabsf(a) < 1e-12f;
      tau = az ? H16 / va : (G[d][c + 1].y - G[d][c].y) / a;
    } else {
      tau = 2.0f;
    }
    tau = fminf(fmaxf(tau, 0.0f), 2.0f);
    G[d][c + 1].z = tau;
  }
  __syncthreads();
  if (tid < 2) {
    float s = 0.0f;
    G[tid][0].z = 0.0f;
    for (int c = 1; c <= 16; ++c) { s += G[tid][c].z; G[tid][c].z = s; }
  }
  __syncthreads();

  const int gid = blockIdx.x * BLOCK + tid;
  const float4 xs = x4[gid];
  float xi[4] = {xs.x, xs.y, xs.z, xs.w};

  // ---- stage A: clamp, cell index, issue g0 reads ----
  float xcl[4]; int c0[4]; float4 g0[4];
#pragma unroll
  for (int p = 0; p < 4; ++p) {
    xcl[p] = fminf(fmaxf(xi[p], 1e-7f), 1.0f - 1e-7f);
    c0[p] = min((int)(xcl[p] * 16.0f), 15);
    g0[p] = G[0][c0[p]];
  }

  // ---- stage B: direction, transcendentals; issue gb + coarse probes ----
  float xw[4], v0[4], lv0[4], ia[4], rv[4];
  int cw[4];
  bool mir[4], az[4];
  const float4* base[4];
  float4 gb[4];
  float pc4[4], pc8[4], pc12[4];
#pragma unroll
  for (int p = 0; p < 4; ++p) {
    float a = g0[p].w;
    float xr = fmaf(-H16, (float)c0[p], xcl[p]);     // x - c0*h (exact)
    float vraw = fmaf(a, xr, g0[p].x);
    mir[p] = vraw < 0.0f;
    v0[p] = fabsf(vraw);                             // |v| in working coords
    xw[p] = mir[p] ? 1.0f - xcl[p] : xcl[p];
    cw[p] = mir[p] ? 15 - c0[p] : c0[p];
    base[p] = G[mir[p] ? 1 : 0];
    lv0[p] = __logf(v0[p]);
    az[p] = fabsf(a) < 1e-12f;
    ia[p] = __builtin_amdgcn_rcpf(az[p] ? 1.0f : a);
    rv[p] = __builtin_amdgcn_rcpf(fmaxf(v0[p], 1e-30f));
    gb[p] = base[p][cw[p] + 1];
    pc4[p]  = base[p][4].z;                          // static-offset probes
    pc8[p]  = base[p][8].z;
    pc12[p] = base[p][12].z;
  }

  // ---- stage C: t0/Tstar, quadrant; issue fine probes ----
  float Tst[4]; int q[4]; float f1[4], f2[4], f3[4];
#pragma unroll
  for (int p = 0; p < 4; ++p) {
    float xb = (float)(cw[p] + 1) * H16;
    float t0 = az[p] ? (xb - xw[p]) * rv[p] : (gb[p].y - lv0[p]) * ia[p];
    if (v0[p] < 1e-15f || gb[p].x <= 0.0f) t0 = SENT;  // stationary / blocked
    float T = 1.0f - t0 + gb[p].z;
    Tst[p] = T;
    int qq = 0;
    qq = (pc4[p]  <= T) ? 4  : qq;
    qq = (pc8[p]  <= T) ? 8  : qq;
    qq = (pc12[p] <= T) ? 12 : qq;
    q[p] = qq;
    const float4* qa = base[p] + qq;
    f1[p] = qa[1].z; f2[p] = qa[2].z; f3[p] = qa[3].z;
  }

  // ---- stage D: final cell index; issue gm ----
  int mf[4]; bool moved[4]; float4 gm[4];
#pragma unroll
  for (int p = 0; p < 4; ++p) {
    float T = Tst[p];
    int m = q[p] + (f1[p] <= T) + (f2[p] <= T) + (f3[p] <= T);
    moved[p] = m > cw[p];
    mf[p] = moved[p] ? m : cw[p];
    gm[p] = base[p][mf[p]];
  }

  // ---- stage E: closed-form finish ----
  float zr[4], ph[4];
#pragma unroll
  for (int p = 0; p < 4; ++p) {
    float am = gm[p].w;
    bool az3 = fabsf(am) < 1e-12f;
    float iam = __builtin_amdgcn_rcpf(az3 ? 1.0f : am);
    float mfh = (float)mf[p] * H16;
    float boa = fmaf(gm[p].x, iam, -mfh);            // b/a from left boundary
    float t_rem = moved[p] ? Tst[p] - gm[p].z : 1.0f;
    float xe = moved[p] ? mfh : xw[p];
    float ve = moved[p] ? gm[p].x : v0[p];
    float zw = az3 ? fmaf(ve, t_rem, xe)
                   : fmaf(xe + boa, __expf(am * t_rem), -boa);
    zr[p] = mir[p] ? 1.0f - zw : zw;
    ph[p] = (moved[p] ? gm[p].y - lv0[p] : 0.0f) + am * t_rem;
  }

  zout[gid] = make_float4(zr[0], zr[1], zr[2], zr[3]);
  pout[gid] = make_float4(ph[0], ph[1], ph[2], ph[3]);
}

extern "C" void kernel_launch(void* const* d_in, const int* in_sizes, int n_in,
                              void* d_out, int out_size, void* d_ws, size_t ws_size,
                              hipStream_t stream) {
  const float4* x4 = (const float4*)d_in[0];
  const float* theta = (const float*)d_in[1];
  float* out = (float*)d_out;
  const int npts = in_sizes[0];  // 16777216
  const int groups = npts / 4;
  const int grid = groups / BLOCK;
  cpab_kernel<<<grid, BLOCK, 0, stream>>>(
      x4, theta, (float4*)out, (float4*)(out + npts), g_B);
}